// Round 2
// baseline (1059.676 us; speedup 1.0000x reference)
//
#include <hip/hip_runtime.h>
#include <hip/hip_bf16.h>
#include <math.h>

#define NN 50000
#define GG 50
#define NODE 1000
#define EE 320000
#define INF 128
#define HEADS 4

// ---------------- CSR build ----------------
__global__ void count_deg(const int* __restrict__ dst, int* __restrict__ deg, int E_) {
    int i = blockIdx.x * 256 + threadIdx.x;
    if (i < E_) atomicAdd(&deg[dst[i]], 1);
}

__global__ void scan1(const int* __restrict__ deg, int* __restrict__ bsum, int Nn) {
    __shared__ int sh[256];
    int i = blockIdx.x * 256 + threadIdx.x;
    sh[threadIdx.x] = (i < Nn) ? deg[i] : 0;
    __syncthreads();
    for (int s = 128; s > 0; s >>= 1) {
        if (threadIdx.x < s) sh[threadIdx.x] += sh[threadIdx.x + s];
        __syncthreads();
    }
    if (threadIdx.x == 0) bsum[blockIdx.x] = sh[0];
}

__global__ void scan2(int* __restrict__ bsum, int nb, int* __restrict__ rowptr, int Nn, int E_) {
    if (threadIdx.x == 0 && blockIdx.x == 0) {
        int acc = 0;
        for (int i = 0; i < nb; ++i) { int v = bsum[i]; bsum[i] = acc; acc += v; }
        rowptr[Nn] = E_;
    }
}

__global__ void scan3(const int* __restrict__ deg, const int* __restrict__ bsum,
                      int* __restrict__ rowptr, int* __restrict__ cursor, int Nn) {
    __shared__ int sh[256];
    int i = blockIdx.x * 256 + threadIdx.x;
    int v = (i < Nn) ? deg[i] : 0;
    sh[threadIdx.x] = v;
    __syncthreads();
    for (int s = 1; s < 256; s <<= 1) {
        int t = (threadIdx.x >= s) ? sh[threadIdx.x - s] : 0;
        __syncthreads();
        sh[threadIdx.x] += t;
        __syncthreads();
    }
    if (i < Nn) {
        int ex = sh[threadIdx.x] - v + bsum[blockIdx.x];
        rowptr[i] = ex;
        cursor[i] = ex;
    }
}

__global__ void scatter_edges(const int* __restrict__ dst, int* __restrict__ cursor,
                              int* __restrict__ eidx, int E_) {
    int i = blockIdx.x * 256 + threadIdx.x;
    if (i < E_) { int pos = atomicAdd(&cursor[dst[i]], 1); eidx[pos] = i; }
}

// ---------------- GEMM: C[M,Ncols] = A[M,KIN] @ W[KIN,Ncols] + bias ----------------
template<int KIN>
__global__ void gemm_bias(const float* __restrict__ A, const float* __restrict__ W,
                          const float* __restrict__ bias, float* __restrict__ C,
                          int M, int Ncols) {
    __shared__ float As[64][33];
    __shared__ float Bs[32][65];
    int tid = threadIdx.x;
    int tr = tid >> 4, tc = tid & 15;
    int row0 = blockIdx.y * 64, col0 = blockIdx.x * 64;
    float acc[4][4] = {};
    for (int k0 = 0; k0 < KIN; k0 += 32) {
        for (int i = tid; i < 64 * 32; i += 256) {
            int r = i >> 5, c = i & 31;
            int gr = row0 + r;
            As[r][c] = (gr < M) ? A[(size_t)gr * KIN + k0 + c] : 0.f;
        }
        for (int i = tid; i < 32 * 64; i += 256) {
            int r = i >> 6, c = i & 63;
            Bs[r][c] = W[(size_t)(k0 + r) * Ncols + col0 + c];
        }
        __syncthreads();
        #pragma unroll
        for (int k = 0; k < 32; ++k) {
            float a[4], b[4];
            #pragma unroll
            for (int i = 0; i < 4; ++i) a[i] = As[tr * 4 + i][k];
            #pragma unroll
            for (int j = 0; j < 4; ++j) b[j] = Bs[k][tc * 4 + j];
            #pragma unroll
            for (int i = 0; i < 4; ++i)
                #pragma unroll
                for (int j = 0; j < 4; ++j) acc[i][j] += a[i] * b[j];
        }
        __syncthreads();
    }
    #pragma unroll
    for (int i = 0; i < 4; ++i) {
        int gr = row0 + tr * 4 + i;
        if (gr < M) {
            #pragma unroll
            for (int j = 0; j < 4; ++j) {
                int gc = col0 + tc * 4 + j;
                C[(size_t)gr * Ncols + gc] = acc[i][j] + bias[gc];
            }
        }
    }
}

// ---------------- edge logits: one wave per edge ----------------
template<int D>
__global__ void edge_logits(const float* __restrict__ fs, const float* __restrict__ fd,
                            const int* __restrict__ src, const int* __restrict__ dst,
                            const float* __restrict__ attn, float* __restrict__ logits, int E_) {
    int lane = threadIdx.x & 63;
    int wave = (blockIdx.x * blockDim.x + threadIdx.x) >> 6;
    int nw = (gridDim.x * blockDim.x) >> 6;
    float at[HEADS][2];
    #pragma unroll
    for (int h = 0; h < HEADS; ++h) {
        if constexpr (D == 64) {
            at[h][0] = attn[h * 64 + lane];
            at[h][1] = 0.f;
        } else {
            at[h][0] = attn[h * 128 + lane];
            at[h][1] = attn[h * 128 + 64 + lane];
        }
    }
    for (int e = wave; e < E_; e += nw) {
        int s = src[e], d = dst[e];
        const float* ps = fs + (size_t)s * (HEADS * D);
        const float* pd = fd + (size_t)d * (HEADS * D);
        #pragma unroll
        for (int h = 0; h < HEADS; ++h) {
            float p;
            if constexpr (D == 64) {
                float v = ps[h * 64 + lane] + pd[h * 64 + lane];
                v = v >= 0.f ? v : 0.2f * v;
                p = v * at[h][0];
            } else {
                float v0 = ps[h * 128 + lane] + pd[h * 128 + lane];
                v0 = v0 >= 0.f ? v0 : 0.2f * v0;
                float v1 = ps[h * 128 + 64 + lane] + pd[h * 128 + 64 + lane];
                v1 = v1 >= 0.f ? v1 : 0.2f * v1;
                p = v0 * at[h][0] + v1 * at[h][1];
            }
            #pragma unroll
            for (int off = 32; off > 0; off >>= 1) p += __shfl_xor(p, off);
            if (lane == 0) logits[(size_t)e * HEADS + h] = p;
        }
    }
}

// ---------------- per (node,head) softmax -> alpha written in place ----------------
__global__ void softmax_alpha(const int* __restrict__ rowptr, const int* __restrict__ eidx,
                              float* __restrict__ logits, int Nn) {
    int t = blockIdx.x * 256 + threadIdx.x;
    if (t >= Nn * HEADS) return;
    int n = t >> 2, h = t & 3;
    int b = rowptr[n], e_ = rowptr[n + 1];
    if (b == e_) return;
    float m = -INFINITY;
    for (int j = b; j < e_; ++j) m = fmaxf(m, logits[(size_t)eidx[j] * HEADS + h]);
    float s = 0.f;
    for (int j = b; j < e_; ++j) s += __expf(logits[(size_t)eidx[j] * HEADS + h] - m);
    float inv = 1.f / s;
    for (int j = b; j < e_; ++j) {
        size_t i = (size_t)eidx[j] * HEADS + h;
        logits[i] = __expf(logits[i] - m) * inv;
    }
}

// ---------------- aggregation + head-max: one wave per node ----------------
template<int D>
__global__ void aggregate(const int* __restrict__ rowptr, const int* __restrict__ eidx,
                          const int* __restrict__ src, const float* __restrict__ alpha,
                          const float* __restrict__ fs, float* __restrict__ hout, int Nn) {
    int lane = threadIdx.x & 63;
    int wave = (blockIdx.x * blockDim.x + threadIdx.x) >> 6;
    int nw = (gridDim.x * blockDim.x) >> 6;
    for (int n = wave; n < Nn; n += nw) {
        int b = rowptr[n], e_ = rowptr[n + 1];
        if constexpr (D == 64) {
            float a0[HEADS] = {0.f, 0.f, 0.f, 0.f};
            for (int j = b; j < e_; ++j) {
                int e = eidx[j];
                int s = src[e];
                const float* p = fs + (size_t)s * 256;
                #pragma unroll
                for (int h = 0; h < HEADS; ++h)
                    a0[h] += alpha[(size_t)e * HEADS + h] * p[h * 64 + lane];
            }
            float r = fmaxf(fmaxf(a0[0], a0[1]), fmaxf(a0[2], a0[3]));
            hout[(size_t)n * 64 + lane] = r;
        } else {
            float a0[HEADS] = {0.f, 0.f, 0.f, 0.f};
            float a1[HEADS] = {0.f, 0.f, 0.f, 0.f};
            for (int j = b; j < e_; ++j) {
                int e = eidx[j];
                int s = src[e];
                const float* p = fs + (size_t)s * 512;
                #pragma unroll
                for (int h = 0; h < HEADS; ++h) {
                    float al = alpha[(size_t)e * HEADS + h];
                    a0[h] += al * p[h * 128 + lane];
                    a1[h] += al * p[h * 128 + 64 + lane];
                }
            }
            float r0 = fmaxf(fmaxf(a0[0], a0[1]), fmaxf(a0[2], a0[3]));
            float r1 = fmaxf(fmaxf(a1[0], a1[1]), fmaxf(a1[2], a1[3]));
            hout[(size_t)n * 128 + lane] = r0;
            hout[(size_t)n * 128 + 64 + lane] = r1;
        }
    }
}

// ---------------- global attention pooling: one block per graph ----------------
__global__ void pool_kernel(const float* __restrict__ h2, const float* __restrict__ gate_w,
                            const float* __restrict__ gate_b, float* __restrict__ out) {
    __shared__ float gate[NODE];
    __shared__ float red[256];
    int g = blockIdx.x;
    int tid = threadIdx.x;
    const float* hb = h2 + (size_t)g * NODE * 128;
    float gb = gate_b[0];
    for (int n = tid; n < NODE; n += 256) {
        const float* r = hb + (size_t)n * 128;
        float acc = 0.f;
        #pragma unroll 8
        for (int k = 0; k < 128; ++k) acc += r[k] * gate_w[k];
        gate[n] = acc + gb;
    }
    __syncthreads();
    float m = -INFINITY;
    for (int n = tid; n < NODE; n += 256) m = fmaxf(m, gate[n]);
    red[tid] = m;
    __syncthreads();
    for (int s = 128; s > 0; s >>= 1) {
        if (tid < s) red[tid] = fmaxf(red[tid], red[tid + s]);
        __syncthreads();
    }
    m = red[0];
    __syncthreads();
    float ssum = 0.f;
    for (int n = tid; n < NODE; n += 256) {
        float e = __expf(gate[n] - m);
        gate[n] = e;
        ssum += e;
    }
    red[tid] = ssum;
    __syncthreads();
    for (int s = 128; s > 0; s >>= 1) {
        if (tid < s) red[tid] += red[tid + s];
        __syncthreads();
    }
    float inv = 1.f / red[0];
    __syncthreads();
    if (tid < 128) {
        float acc = 0.f;
        for (int n = 0; n < NODE; ++n) acc += gate[n] * hb[(size_t)n * 128 + tid];
        out[g * 128 + tid] = acc * inv;
    }
}

extern "C" void kernel_launch(void* const* d_in, const int* in_sizes, int n_in,
                              void* d_out, int out_size, void* d_ws, size_t ws_size,
                              hipStream_t stream) {
    const float* x      = (const float*)d_in[0];
    const int*   src    = (const int*)d_in[1];
    const int*   dst    = (const int*)d_in[2];
    // d_in[3] node2graph: implicit (contiguous blocks of 1000)
    const float* W_src1 = (const float*)d_in[4];
    const float* b_src1 = (const float*)d_in[5];
    const float* W_dst1 = (const float*)d_in[6];
    const float* b_dst1 = (const float*)d_in[7];
    const float* attn1  = (const float*)d_in[8];
    const float* W_src2 = (const float*)d_in[9];
    const float* b_src2 = (const float*)d_in[10];
    const float* W_dst2 = (const float*)d_in[11];
    const float* b_dst2 = (const float*)d_in[12];
    const float* attn2  = (const float*)d_in[13];
    const float* gate_w = (const float*)d_in[14];
    const float* gate_b = (const float*)d_in[15];
    float* out = (float*)d_out;

    char* p = (char*)d_ws;
    auto alloc = [&](size_t bytes) -> void* {
        void* r = (void*)p;
        p += (bytes + 255) & ~(size_t)255;
        return r;
    };
    float* fs     = (float*)alloc((size_t)NN * 512 * 4);
    float* fd     = (float*)alloc((size_t)NN * 512 * 4);
    float* h1     = (float*)alloc((size_t)NN * 64 * 4);
    float* h2     = (float*)alloc((size_t)NN * 128 * 4);
    float* logits = (float*)alloc((size_t)EE * HEADS * 4);
    int*   deg    = (int*)alloc((size_t)NN * 4);
    int*   rowptr = (int*)alloc((size_t)(NN + 1) * 4);
    int*   cursor = (int*)alloc((size_t)NN * 4);
    int*   eidx   = (int*)alloc((size_t)EE * 4);
    int*   bsum   = (int*)alloc(4096);

    // ---- CSR build (dst-indexed) ----
    hipMemsetAsync(deg, 0, (size_t)NN * 4, stream);
    count_deg<<<(EE + 255) / 256, 256, 0, stream>>>(dst, deg, EE);
    int nb = (NN + 255) / 256;
    scan1<<<nb, 256, 0, stream>>>(deg, bsum, NN);
    scan2<<<1, 64, 0, stream>>>(bsum, nb, rowptr, NN, EE);
    scan3<<<nb, 256, 0, stream>>>(deg, bsum, rowptr, cursor, NN);
    scatter_edges<<<(EE + 255) / 256, 256, 0, stream>>>(dst, cursor, eidx, EE);

    int rowtiles = (NN + 63) / 64; // 782

    // ---- layer 1 (D=64, HD=256) ----
    gemm_bias<128><<<dim3(4, rowtiles), 256, 0, stream>>>(x, W_src1, b_src1, fs, NN, 256);
    gemm_bias<128><<<dim3(4, rowtiles), 256, 0, stream>>>(x, W_dst1, b_dst1, fd, NN, 256);
    edge_logits<64><<<2048, 256, 0, stream>>>(fs, fd, src, dst, attn1, logits, EE);
    softmax_alpha<<<(NN * HEADS + 255) / 256, 256, 0, stream>>>(rowptr, eidx, logits, NN);
    aggregate<64><<<2048, 256, 0, stream>>>(rowptr, eidx, src, logits, fs, h1, NN);

    // ---- layer 2 (D=128, HD=512) ----
    gemm_bias<64><<<dim3(8, rowtiles), 256, 0, stream>>>(h1, W_src2, b_src2, fs, NN, 512);
    gemm_bias<64><<<dim3(8, rowtiles), 256, 0, stream>>>(h1, W_dst2, b_dst2, fd, NN, 512);
    edge_logits<128><<<2048, 256, 0, stream>>>(fs, fd, src, dst, attn2, logits, EE);
    softmax_alpha<<<(NN * HEADS + 255) / 256, 256, 0, stream>>>(rowptr, eidx, logits, NN);
    aggregate<128><<<2048, 256, 0, stream>>>(rowptr, eidx, src, logits, fs, h2, NN);

    // ---- global attention pooling ----
    pool_kernel<<<GG, 256, 0, stream>>>(h2, gate_w, gate_b, out);
}

// Round 5
// 734.905 us; speedup vs baseline: 1.4419x; 1.4419x over previous
//
#include <hip/hip_runtime.h>
#include <math.h>

#define NN 50000
#define GG 50
#define NODE 1000
#define EE 320000
#define HEADS 4

typedef __attribute__((ext_vector_type(8))) short short8;
typedef __attribute__((ext_vector_type(8))) __bf16 bf16x8;
typedef __attribute__((ext_vector_type(4))) float f32x4;

__device__ __forceinline__ unsigned short f2bf(float f) {
    unsigned int u = __float_as_uint(f);
    u = (u + 0x7fffu + ((u >> 16) & 1u)) >> 16;
    return (unsigned short)u;
}
__device__ __forceinline__ float bf2f(unsigned short s) {
    return __uint_as_float(((unsigned int)s) << 16);
}

// ---------------- dtype conversion kernels ----------------
__global__ void cvt_f32_bf16(const float* __restrict__ in, unsigned short* __restrict__ outp, int n4) {
    int i = blockIdx.x * 256 + threadIdx.x;
    if (i < n4) {
        float4 f = *(const float4*)(in + (size_t)i * 4);
        ushort4 o;
        o.x = f2bf(f.x); o.y = f2bf(f.y); o.z = f2bf(f.z); o.w = f2bf(f.w);
        *(ushort4*)(outp + (size_t)i * 4) = o;
    }
}

// W[K][N] fp32 -> Wt[N][K] bf16
__global__ void wt_cvt(const float* __restrict__ W, unsigned short* __restrict__ Wt, int K, int N_) {
    int i = blockIdx.x * 256 + threadIdx.x;
    if (i < K * N_) {
        int n = i / K, k = i - n * K;
        Wt[i] = f2bf(W[(size_t)k * N_ + n]);
    }
}

// ---------------- CSR build ----------------
__global__ void count_deg(const int* __restrict__ dst, int* __restrict__ deg, int E_) {
    int i = blockIdx.x * 256 + threadIdx.x;
    if (i < E_) atomicAdd(&deg[dst[i]], 1);
}

__global__ void scan1(const int* __restrict__ deg, int* __restrict__ bsum, int Nn) {
    __shared__ int sh[256];
    int i = blockIdx.x * 256 + threadIdx.x;
    sh[threadIdx.x] = (i < Nn) ? deg[i] : 0;
    __syncthreads();
    for (int s = 128; s > 0; s >>= 1) {
        if (threadIdx.x < s) sh[threadIdx.x] += sh[threadIdx.x + s];
        __syncthreads();
    }
    if (threadIdx.x == 0) bsum[blockIdx.x] = sh[0];
}

__global__ void scan2(int* __restrict__ bsum, int nb, int* __restrict__ rowptr, int Nn, int E_) {
    if (threadIdx.x == 0 && blockIdx.x == 0) {
        int acc = 0;
        for (int i = 0; i < nb; ++i) { int v = bsum[i]; bsum[i] = acc; acc += v; }
        rowptr[Nn] = E_;
    }
}

__global__ void scan3(const int* __restrict__ deg, const int* __restrict__ bsum,
                      int* __restrict__ rowptr, int* __restrict__ cursor, int Nn) {
    __shared__ int sh[256];
    int i = blockIdx.x * 256 + threadIdx.x;
    int v = (i < Nn) ? deg[i] : 0;
    sh[threadIdx.x] = v;
    __syncthreads();
    for (int s = 1; s < 256; s <<= 1) {
        int t = (threadIdx.x >= s) ? sh[threadIdx.x - s] : 0;
        __syncthreads();
        sh[threadIdx.x] += t;
        __syncthreads();
    }
    if (i < Nn) {
        int ex = sh[threadIdx.x] - v + bsum[blockIdx.x];
        rowptr[i] = ex;
        cursor[i] = ex;
    }
}

__global__ void scatter_edges(const int* __restrict__ dst, int* __restrict__ cursor,
                              int* __restrict__ eidx, int E_) {
    int i = blockIdx.x * 256 + threadIdx.x;
    if (i < E_) { int pos = atomicAdd(&cursor[dst[i]], 1); eidx[pos] = i; }
}

// ---------------- bf16 MFMA GEMM ----------------
// C[M,Ncols](f32) = A[M,K](bf16) @ Wt[Ncols,K](bf16)^T + bias
// 128x128 tile, 4 waves (2x2), full K in LDS, XOR-swizzled for conflict-free ds_read_b128.
template<int K>
__global__ __launch_bounds__(256)
void gemm_mfma(const unsigned short* __restrict__ A, const unsigned short* __restrict__ Wt,
               const float* __restrict__ bias, float* __restrict__ C,
               int M, int Ncols) {
    __shared__ short A_lds[128 * K];
    __shared__ short B_lds[128 * K];
    constexpr int CH = K / 8;          // 16B chunks per row
    constexpr int ROWB = K * 2;        // bytes per LDS row
    int tid = threadIdx.x;
    int lane = tid & 63, wave = tid >> 6;
    int row0 = blockIdx.y * 128, col0 = blockIdx.x * 128;

    // stage A (rows row0..row0+127, all K), swizzled
    for (int c = tid; c < 128 * CH; c += 256) {
        int r = c / CH, kc = c - r * CH;
        int gr = row0 + r; if (gr >= M) gr = M - 1;
        short8 v = *(const short8*)(A + (size_t)gr * K + kc * 8);
        *(short8*)((char*)A_lds + r * ROWB + ((kc * 16) ^ ((r & 7) << 4))) = v;
    }
    // stage B: Wt rows col0..col0+127
    for (int c = tid; c < 128 * CH; c += 256) {
        int r = c / CH, kc = c - r * CH;
        short8 v = *(const short8*)(Wt + (size_t)(col0 + r) * K + kc * 8);
        *(short8*)((char*)B_lds + r * ROWB + ((kc * 16) ^ ((r & 7) << 4))) = v;
    }
    __syncthreads();

    int wr = wave >> 1, wc = wave & 1;
    f32x4 acc[4][4] = {};
    #pragma unroll
    for (int ks = 0; ks < K / 32; ++ks) {
        int kbyte = ks * 64 + ((lane >> 4) << 4);
        short8 a[4], b[4];
        #pragma unroll
        for (int m = 0; m < 4; ++m) {
            int r = wr * 64 + m * 16 + (lane & 15);
            a[m] = *(const short8*)((const char*)A_lds + r * ROWB + (kbyte ^ ((r & 7) << 4)));
        }
        #pragma unroll
        for (int n = 0; n < 4; ++n) {
            int r = wc * 64 + n * 16 + (lane & 15);
            b[n] = *(const short8*)((const char*)B_lds + r * ROWB + (kbyte ^ ((r & 7) << 4)));
        }
        #pragma unroll
        for (int m = 0; m < 4; ++m)
            #pragma unroll
            for (int n = 0; n < 4; ++n)
                acc[m][n] = __builtin_amdgcn_mfma_f32_16x16x32_bf16(
                    __builtin_bit_cast(bf16x8, a[m]), __builtin_bit_cast(bf16x8, b[n]),
                    acc[m][n], 0, 0, 0);
    }

    // epilogue: D mapping col=lane&15, row=(lane>>4)*4+q
    #pragma unroll
    for (int m = 0; m < 4; ++m) {
        int grb = row0 + wr * 64 + m * 16 + ((lane >> 4) << 2);
        #pragma unroll
        for (int q = 0; q < 4; ++q) {
            int gr = grb + q;
            if (gr < M) {
                #pragma unroll
                for (int n = 0; n < 4; ++n) {
                    int gc = col0 + wc * 64 + n * 16 + (lane & 15);
                    C[(size_t)gr * Ncols + gc] = acc[m][n][q] + bias[gc];
                }
            }
        }
    }
}

// ---------------- edge logits: one wave per edge ----------------
template<int D>
__global__ void edge_logits(const float* __restrict__ fs, const float* __restrict__ fd,
                            const int* __restrict__ src, const int* __restrict__ dst,
                            const float* __restrict__ attn, float* __restrict__ logits, int E_) {
    int lane = threadIdx.x & 63;
    int wave = (blockIdx.x * blockDim.x + threadIdx.x) >> 6;
    int nw = (gridDim.x * blockDim.x) >> 6;
    float at[HEADS][2];
    #pragma unroll
    for (int h = 0; h < HEADS; ++h) {
        if constexpr (D == 64) {
            at[h][0] = attn[h * 64 + lane];
            at[h][1] = 0.f;
        } else {
            at[h][0] = attn[h * 128 + lane];
            at[h][1] = attn[h * 128 + 64 + lane];
        }
    }
    for (int e = wave; e < E_; e += nw) {
        int s = src[e], d = dst[e];
        const float* ps = fs + (size_t)s * (HEADS * D);
        const float* pd = fd + (size_t)d * (HEADS * D);
        #pragma unroll
        for (int h = 0; h < HEADS; ++h) {
            float p;
            if constexpr (D == 64) {
                float v = ps[h * 64 + lane] + pd[h * 64 + lane];
                v = v >= 0.f ? v : 0.2f * v;
                p = v * at[h][0];
            } else {
                float v0 = ps[h * 128 + lane] + pd[h * 128 + lane];
                v0 = v0 >= 0.f ? v0 : 0.2f * v0;
                float v1 = ps[h * 128 + 64 + lane] + pd[h * 128 + 64 + lane];
                v1 = v1 >= 0.f ? v1 : 0.2f * v1;
                p = v0 * at[h][0] + v1 * at[h][1];
            }
            #pragma unroll
            for (int off = 32; off > 0; off >>= 1) p += __shfl_xor(p, off);
            if (lane == 0) logits[(size_t)e * HEADS + h] = p;
        }
    }
}

// ---------------- per (node,head) softmax -> alpha in place ----------------
__global__ void softmax_alpha(const int* __restrict__ rowptr, const int* __restrict__ eidx,
                              float* __restrict__ logits, int Nn) {
    int t = blockIdx.x * 256 + threadIdx.x;
    if (t >= Nn * HEADS) return;
    int n = t >> 2, h = t & 3;
    int b = rowptr[n], e_ = rowptr[n + 1];
    if (b == e_) return;
    float m = -INFINITY;
    for (int j = b; j < e_; ++j) m = fmaxf(m, logits[(size_t)eidx[j] * HEADS + h]);
    float s = 0.f;
    for (int j = b; j < e_; ++j) s += __expf(logits[(size_t)eidx[j] * HEADS + h] - m);
    float inv = 1.f / s;
    for (int j = b; j < e_; ++j) {
        size_t i = (size_t)eidx[j] * HEADS + h;
        logits[i] = __expf(logits[i] - m) * inv;
    }
}

// ---------------- aggregation + head-max: one wave per node ----------------
// D=64 writes bf16 (feeds GEMM2); D=128 writes f32 (feeds pool)
template<int D>
__global__ void aggregate(const int* __restrict__ rowptr, const int* __restrict__ eidx,
                          const int* __restrict__ src, const float* __restrict__ alpha,
                          const float* __restrict__ fs, void* __restrict__ hout, int Nn) {
    int lane = threadIdx.x & 63;
    int wave = (blockIdx.x * blockDim.x + threadIdx.x) >> 6;
    int nw = (gridDim.x * blockDim.x) >> 6;
    for (int n = wave; n < Nn; n += nw) {
        int b = rowptr[n], e_ = rowptr[n + 1];
        if constexpr (D == 64) {
            float a0[HEADS] = {0.f, 0.f, 0.f, 0.f};
            for (int j = b; j < e_; ++j) {
                int e = eidx[j];
                int s = src[e];
                const float* p = fs + (size_t)s * 256;
                #pragma unroll
                for (int h = 0; h < HEADS; ++h)
                    a0[h] += alpha[(size_t)e * HEADS + h] * p[h * 64 + lane];
            }
            float r = fmaxf(fmaxf(a0[0], a0[1]), fmaxf(a0[2], a0[3]));
            ((unsigned short*)hout)[(size_t)n * 64 + lane] = f2bf(r);
        } else {
            float a0[HEADS] = {0.f, 0.f, 0.f, 0.f};
            float a1[HEADS] = {0.f, 0.f, 0.f, 0.f};
            for (int j = b; j < e_; ++j) {
                int e = eidx[j];
                int s = src[e];
                const float* p = fs + (size_t)s * 512;
                #pragma unroll
                for (int h = 0; h < HEADS; ++h) {
                    float al = alpha[(size_t)e * HEADS + h];
                    a0[h] += al * p[h * 128 + lane];
                    a1[h] += al * p[h * 128 + 64 + lane];
                }
            }
            float r0 = fmaxf(fmaxf(a0[0], a0[1]), fmaxf(a0[2], a0[3]));
            float r1 = fmaxf(fmaxf(a1[0], a1[1]), fmaxf(a1[2], a1[3]));
            ((float*)hout)[(size_t)n * 128 + lane] = r0;
            ((float*)hout)[(size_t)n * 128 + 64 + lane] = r1;
        }
    }
}

// ---------------- global attention pooling: one block per graph ----------------
__global__ void pool_kernel(const float* __restrict__ h2, const float* __restrict__ gate_w,
                            const float* __restrict__ gate_b, float* __restrict__ out) {
    __shared__ float gate[NODE];
    __shared__ float red[256];
    int g = blockIdx.x;
    int tid = threadIdx.x;
    const float* hb = h2 + (size_t)g * NODE * 128;
    float gb = gate_b[0];
    for (int n = tid; n < NODE; n += 256) {
        const float* r = hb + (size_t)n * 128;
        float acc = 0.f;
        #pragma unroll 8
        for (int k = 0; k < 128; ++k) acc += r[k] * gate_w[k];
        gate[n] = acc + gb;
    }
    __syncthreads();
    float m = -INFINITY;
    for (int n = tid; n < NODE; n += 256) m = fmaxf(m, gate[n]);
    red[tid] = m;
    __syncthreads();
    for (int s = 128; s > 0; s >>= 1) {
        if (tid < s) red[tid] = fmaxf(red[tid], red[tid + s]);
        __syncthreads();
    }
    m = red[0];
    __syncthreads();
    float ssum = 0.f;
    for (int n = tid; n < NODE; n += 256) {
        float e = __expf(gate[n] - m);
        gate[n] = e;
        ssum += e;
    }
    red[tid] = ssum;
    __syncthreads();
    for (int s = 128; s > 0; s >>= 1) {
        if (tid < s) red[tid] += red[tid + s];
        __syncthreads();
    }
    float inv = 1.f / red[0];
    __syncthreads();
    if (tid < 128) {
        float acc = 0.f;
        for (int n = 0; n < NODE; ++n) acc += gate[n] * hb[(size_t)n * 128 + tid];
        out[g * 128 + tid] = acc * inv;
    }
}

extern "C" void kernel_launch(void* const* d_in, const int* in_sizes, int n_in,
                              void* d_out, int out_size, void* d_ws, size_t ws_size,
                              hipStream_t stream) {
    const float* x      = (const float*)d_in[0];
    const int*   src    = (const int*)d_in[1];
    const int*   dst    = (const int*)d_in[2];
    // d_in[3] node2graph: implicit (contiguous blocks of 1000)
    const float* W_src1 = (const float*)d_in[4];
    const float* b_src1 = (const float*)d_in[5];
    const float* W_dst1 = (const float*)d_in[6];
    const float* b_dst1 = (const float*)d_in[7];
    const float* attn1  = (const float*)d_in[8];
    const float* W_src2 = (const float*)d_in[9];
    const float* b_src2 = (const float*)d_in[10];
    const float* W_dst2 = (const float*)d_in[11];
    const float* b_dst2 = (const float*)d_in[12];
    const float* attn2  = (const float*)d_in[13];
    const float* gate_w = (const float*)d_in[14];
    const float* gate_b = (const float*)d_in[15];
    float* out = (float*)d_out;

    char* p = (char*)d_ws;
    auto alloc = [&](size_t bytes) -> void* {
        void* r = (void*)p;
        p += (bytes + 255) & ~(size_t)255;
        return r;
    };
    float*          fs     = (float*)alloc((size_t)NN * 512 * 4);
    float*          fd     = (float*)alloc((size_t)NN * 512 * 4);
    unsigned short* h1     = (unsigned short*)alloc((size_t)NN * 64 * 2);
    float*          h2     = (float*)alloc((size_t)NN * 128 * 4);
    float*          logits = (float*)alloc((size_t)EE * HEADS * 4);
    unsigned short* x_bf   = (unsigned short*)alloc((size_t)NN * 128 * 2);
    unsigned short* Wt1s   = (unsigned short*)alloc((size_t)128 * 256 * 2);
    unsigned short* Wt1d   = (unsigned short*)alloc((size_t)128 * 256 * 2);
    unsigned short* Wt2s   = (unsigned short*)alloc((size_t)64 * 512 * 2);
    unsigned short* Wt2d   = (unsigned short*)alloc((size_t)64 * 512 * 2);
    int*            deg    = (int*)alloc((size_t)NN * 4);
    int*            rowptr = (int*)alloc((size_t)(NN + 1) * 4);
    int*            cursor = (int*)alloc((size_t)NN * 4);
    int*            eidx   = (int*)alloc((size_t)EE * 4);
    int*            bsum   = (int*)alloc(4096);

    // ---- dtype prep ----
    cvt_f32_bf16<<<(NN * 128 / 4 + 255) / 256, 256, 0, stream>>>(x, x_bf, NN * 128 / 4);
    wt_cvt<<<(128 * 256 + 255) / 256, 256, 0, stream>>>(W_src1, Wt1s, 128, 256);
    wt_cvt<<<(128 * 256 + 255) / 256, 256, 0, stream>>>(W_dst1, Wt1d, 128, 256);
    wt_cvt<<<(64 * 512 + 255) / 256, 256, 0, stream>>>(W_src2, Wt2s, 64, 512);
    wt_cvt<<<(64 * 512 + 255) / 256, 256, 0, stream>>>(W_dst2, Wt2d, 64, 512);

    // ---- CSR build (dst-indexed) ----
    hipMemsetAsync(deg, 0, (size_t)NN * 4, stream);
    count_deg<<<(EE + 255) / 256, 256, 0, stream>>>(dst, deg, EE);
    int nb = (NN + 255) / 256;
    scan1<<<nb, 256, 0, stream>>>(deg, bsum, NN);
    scan2<<<1, 64, 0, stream>>>(bsum, nb, rowptr, NN, EE);
    scan3<<<nb, 256, 0, stream>>>(deg, bsum, rowptr, cursor, NN);
    scatter_edges<<<(EE + 255) / 256, 256, 0, stream>>>(dst, cursor, eidx, EE);

    int rowtiles = (NN + 127) / 128; // 391

    // ---- layer 1 (D=64, HD=256, K=128) ----
    gemm_mfma<128><<<dim3(2, rowtiles), 256, 0, stream>>>(x_bf, Wt1s, b_src1, fs, NN, 256);
    gemm_mfma<128><<<dim3(2, rowtiles), 256, 0, stream>>>(x_bf, Wt1d, b_dst1, fd, NN, 256);
    edge_logits<64><<<2048, 256, 0, stream>>>(fs, fd, src, dst, attn1, logits, EE);
    softmax_alpha<<<(NN * HEADS + 255) / 256, 256, 0, stream>>>(rowptr, eidx, logits, NN);
    aggregate<64><<<2048, 256, 0, stream>>>(rowptr, eidx, src, logits, fs, h1, NN);

    // ---- layer 2 (D=128, HD=512, K=64) ----
    gemm_mfma<64><<<dim3(4, rowtiles), 256, 0, stream>>>(h1, Wt2s, b_src2, fs, NN, 512);
    gemm_mfma<64><<<dim3(4, rowtiles), 256, 0, stream>>>(h1, Wt2d, b_dst2, fd, NN, 512);
    edge_logits<128><<<2048, 256, 0, stream>>>(fs, fd, src, dst, attn2, logits, EE);
    softmax_alpha<<<(NN * HEADS + 255) / 256, 256, 0, stream>>>(rowptr, eidx, logits, NN);
    aggregate<128><<<2048, 256, 0, stream>>>(rowptr, eidx, src, logits, fs, h2, NN);

    // ---- global attention pooling ----
    pool_kernel<<<GG, 256, 0, stream>>>(h2, gate_w, gate_b, out);
}

// Round 6
// 559.850 us; speedup vs baseline: 1.8928x; 1.3127x over previous
//
#include <hip/hip_runtime.h>
#include <math.h>

#define NN 50000
#define GG 50
#define NODE 1000
#define EE 320000
#define HEADS 4

typedef __attribute__((ext_vector_type(8))) short short8;
typedef __attribute__((ext_vector_type(8))) __bf16 bf16x8;
typedef __attribute__((ext_vector_type(4))) float f32x4;

__device__ __forceinline__ unsigned short f2bf(float f) {
    unsigned int u = __float_as_uint(f);
    u = (u + 0x7fffu + ((u >> 16) & 1u)) >> 16;
    return (unsigned short)u;
}
__device__ __forceinline__ float bf2f(unsigned short s) {
    return __uint_as_float(((unsigned int)s) << 16);
}

// ---------------- dtype conversion kernels ----------------
__global__ void cvt_f32_bf16(const float* __restrict__ in, unsigned short* __restrict__ outp, int n4) {
    int i = blockIdx.x * 256 + threadIdx.x;
    if (i < n4) {
        float4 f = *(const float4*)(in + (size_t)i * 4);
        ushort4 o;
        o.x = f2bf(f.x); o.y = f2bf(f.y); o.z = f2bf(f.z); o.w = f2bf(f.w);
        *(ushort4*)(outp + (size_t)i * 4) = o;
    }
}

// W[K][N] fp32 -> Wt[N][K] bf16
__global__ void wt_cvt(const float* __restrict__ W, unsigned short* __restrict__ Wt, int K, int N_) {
    int i = blockIdx.x * 256 + threadIdx.x;
    if (i < K * N_) {
        int n = i / K, k = i - n * K;
        Wt[i] = f2bf(W[(size_t)k * N_ + n]);
    }
}

// ---------------- CSR build ----------------
__global__ void count_deg(const int* __restrict__ dst, int* __restrict__ deg, int E_) {
    int i = blockIdx.x * 256 + threadIdx.x;
    if (i < E_) atomicAdd(&deg[dst[i]], 1);
}

__global__ void scan1(const int* __restrict__ deg, int* __restrict__ bsum, int Nn) {
    __shared__ int sh[256];
    int i = blockIdx.x * 256 + threadIdx.x;
    sh[threadIdx.x] = (i < Nn) ? deg[i] : 0;
    __syncthreads();
    for (int s = 128; s > 0; s >>= 1) {
        if (threadIdx.x < s) sh[threadIdx.x] += sh[threadIdx.x + s];
        __syncthreads();
    }
    if (threadIdx.x == 0) bsum[blockIdx.x] = sh[0];
}

__global__ void scan2(int* __restrict__ bsum, int nb, int* __restrict__ rowptr, int Nn, int E_) {
    if (threadIdx.x == 0 && blockIdx.x == 0) {
        int acc = 0;
        for (int i = 0; i < nb; ++i) { int v = bsum[i]; bsum[i] = acc; acc += v; }
        rowptr[Nn] = E_;
    }
}

__global__ void scan3(const int* __restrict__ deg, const int* __restrict__ bsum,
                      int* __restrict__ rowptr, int* __restrict__ cursor, int Nn) {
    __shared__ int sh[256];
    int i = blockIdx.x * 256 + threadIdx.x;
    int v = (i < Nn) ? deg[i] : 0;
    sh[threadIdx.x] = v;
    __syncthreads();
    for (int s = 1; s < 256; s <<= 1) {
        int t = (threadIdx.x >= s) ? sh[threadIdx.x - s] : 0;
        __syncthreads();
        sh[threadIdx.x] += t;
        __syncthreads();
    }
    if (i < Nn) {
        int ex = sh[threadIdx.x] - v + bsum[blockIdx.x];
        rowptr[i] = ex;
        cursor[i] = ex;
    }
}

__global__ void scatter_edges(const int* __restrict__ dst, int* __restrict__ cursor,
                              int* __restrict__ eidx, int E_) {
    int i = blockIdx.x * 256 + threadIdx.x;
    if (i < E_) { int pos = atomicAdd(&cursor[dst[i]], 1); eidx[pos] = i; }
}

// ---------------- bf16 MFMA GEMM, bf16 output ----------------
// C[M,Ncols](bf16) = A[M,K](bf16) @ Wt[Ncols,K](bf16)^T + bias
template<int K>
__global__ __launch_bounds__(256)
void gemm_mfma(const unsigned short* __restrict__ A, const unsigned short* __restrict__ Wt,
               const float* __restrict__ bias, unsigned short* __restrict__ C,
               int M, int Ncols) {
    __shared__ short A_lds[128 * K];
    __shared__ short B_lds[128 * K];
    constexpr int CH = K / 8;          // 16B chunks per row
    constexpr int ROWB = K * 2;        // bytes per LDS row
    int tid = threadIdx.x;
    int lane = tid & 63, wave = tid >> 6;
    int row0 = blockIdx.y * 128, col0 = blockIdx.x * 128;

    for (int c = tid; c < 128 * CH; c += 256) {
        int r = c / CH, kc = c - r * CH;
        int gr = row0 + r; if (gr >= M) gr = M - 1;
        short8 v = *(const short8*)(A + (size_t)gr * K + kc * 8);
        *(short8*)((char*)A_lds + r * ROWB + ((kc * 16) ^ ((r & 7) << 4))) = v;
    }
    for (int c = tid; c < 128 * CH; c += 256) {
        int r = c / CH, kc = c - r * CH;
        short8 v = *(const short8*)(Wt + (size_t)(col0 + r) * K + kc * 8);
        *(short8*)((char*)B_lds + r * ROWB + ((kc * 16) ^ ((r & 7) << 4))) = v;
    }
    __syncthreads();

    int wr = wave >> 1, wc = wave & 1;
    f32x4 acc[4][4] = {};
    #pragma unroll
    for (int ks = 0; ks < K / 32; ++ks) {
        int kbyte = ks * 64 + ((lane >> 4) << 4);
        short8 a[4], b[4];
        #pragma unroll
        for (int m = 0; m < 4; ++m) {
            int r = wr * 64 + m * 16 + (lane & 15);
            a[m] = *(const short8*)((const char*)A_lds + r * ROWB + (kbyte ^ ((r & 7) << 4)));
        }
        #pragma unroll
        for (int n = 0; n < 4; ++n) {
            int r = wc * 64 + n * 16 + (lane & 15);
            b[n] = *(const short8*)((const char*)B_lds + r * ROWB + (kbyte ^ ((r & 7) << 4)));
        }
        #pragma unroll
        for (int m = 0; m < 4; ++m)
            #pragma unroll
            for (int n = 0; n < 4; ++n)
                acc[m][n] = __builtin_amdgcn_mfma_f32_16x16x32_bf16(
                    __builtin_bit_cast(bf16x8, a[m]), __builtin_bit_cast(bf16x8, b[n]),
                    acc[m][n], 0, 0, 0);
    }

    // epilogue: D mapping col=lane&15, row=(lane>>4)*4+q ; write bf16
    #pragma unroll
    for (int m = 0; m < 4; ++m) {
        int grb = row0 + wr * 64 + m * 16 + ((lane >> 4) << 2);
        #pragma unroll
        for (int q = 0; q < 4; ++q) {
            int gr = grb + q;
            if (gr < M) {
                #pragma unroll
                for (int n = 0; n < 4; ++n) {
                    int gc = col0 + wc * 64 + n * 16 + (lane & 15);
                    C[(size_t)gr * Ncols + gc] = f2bf(acc[m][n][q] + bias[gc]);
                }
            }
        }
    }
}

// ---------------- edge logits (bf16 rows): one wave per edge ----------------
// Lane owns head = lane>>4, dim-chunk = (lane&15)*VE .. +VE-1 (VE=D/16 elems)
template<int D>
__global__ void edge_logits(const unsigned short* __restrict__ fs, const unsigned short* __restrict__ fd,
                            const int* __restrict__ src, const int* __restrict__ dst,
                            const float* __restrict__ attn, float* __restrict__ logits, int E_) {
    int lane = threadIdx.x & 63;
    int wave = (blockIdx.x * blockDim.x + threadIdx.x) >> 6;
    int nw = (gridDim.x * blockDim.x) >> 6;
    constexpr int VE = D / 16;            // elems per lane (4 or 8)
    constexpr int HD = HEADS * D;         // row length
    int head = lane >> 4;
    int doff = (lane & 15) * VE;
    float at[VE];
    #pragma unroll
    for (int j = 0; j < VE; ++j) at[j] = attn[head * D + doff + j];

    for (int e = wave; e < E_; e += nw) {
        int s = src[e], d = dst[e];
        float p = 0.f;
        if constexpr (VE == 4) {
            ushort4 vs = *(const ushort4*)(fs + (size_t)s * HD + lane * 4);
            ushort4 vd = *(const ushort4*)(fd + (size_t)d * HD + lane * 4);
            unsigned short es[4] = {vs.x, vs.y, vs.z, vs.w};
            unsigned short ed[4] = {vd.x, vd.y, vd.z, vd.w};
            #pragma unroll
            for (int j = 0; j < 4; ++j) {
                float v = bf2f(es[j]) + bf2f(ed[j]);
                v = v >= 0.f ? v : 0.2f * v;
                p += v * at[j];
            }
        } else {
            short8 vs = *(const short8*)(fs + (size_t)s * HD + lane * 8);
            short8 vd = *(const short8*)(fd + (size_t)d * HD + lane * 8);
            #pragma unroll
            for (int j = 0; j < 8; ++j) {
                float v = bf2f((unsigned short)vs[j]) + bf2f((unsigned short)vd[j]);
                v = v >= 0.f ? v : 0.2f * v;
                p += v * at[j];
            }
        }
        // reduce within each 16-lane head group
        p += __shfl_xor(p, 1);
        p += __shfl_xor(p, 2);
        p += __shfl_xor(p, 4);
        p += __shfl_xor(p, 8);
        if ((lane & 15) == 0) logits[(size_t)e * HEADS + head] = p;
    }
}

// ---------------- per (node,head) softmax -> alpha in place ----------------
__global__ void softmax_alpha(const int* __restrict__ rowptr, const int* __restrict__ eidx,
                              float* __restrict__ logits, int Nn) {
    int t = blockIdx.x * 256 + threadIdx.x;
    if (t >= Nn * HEADS) return;
    int n = t >> 2, h = t & 3;
    int b = rowptr[n], e_ = rowptr[n + 1];
    if (b == e_) return;
    float m = -INFINITY;
    for (int j = b; j < e_; ++j) m = fmaxf(m, logits[(size_t)eidx[j] * HEADS + h]);
    float s = 0.f;
    for (int j = b; j < e_; ++j) s += __expf(logits[(size_t)eidx[j] * HEADS + h] - m);
    float inv = 1.f / s;
    for (int j = b; j < e_; ++j) {
        size_t i = (size_t)eidx[j] * HEADS + h;
        logits[i] = __expf(logits[i] - m) * inv;
    }
}

// ---------------- aggregation + head-max (bf16 fs): one wave per node ----------------
// Lane owns head=lane>>4, dim-chunk (lane&15)*VE. Head-max folds via shfl_xor 16,32.
// D=64 -> hout bf16 [NN][64]; D=128 -> hout f32 [NN][128]
template<int D>
__global__ void aggregate(const int* __restrict__ rowptr, const int* __restrict__ eidx,
                          const int* __restrict__ src, const float* __restrict__ alpha,
                          const unsigned short* __restrict__ fs, void* __restrict__ hout, int Nn) {
    int lane = threadIdx.x & 63;
    int wave = (blockIdx.x * blockDim.x + threadIdx.x) >> 6;
    int nw = (gridDim.x * blockDim.x) >> 6;
    constexpr int VE = D / 16;
    constexpr int HD = HEADS * D;
    int head = lane >> 4;
    int doff = (lane & 15) * VE;

    for (int n = wave; n < Nn; n += nw) {
        int b = rowptr[n], e_ = rowptr[n + 1];
        float acc[VE];
        #pragma unroll
        for (int j = 0; j < VE; ++j) acc[j] = 0.f;

        for (int j = b; j < e_; ++j) {
            int e = eidx[j];
            int s = src[e];
            float al = alpha[(size_t)e * HEADS + head];
            if constexpr (VE == 4) {
                ushort4 vs = *(const ushort4*)(fs + (size_t)s * HD + lane * 4);
                acc[0] += al * bf2f(vs.x);
                acc[1] += al * bf2f(vs.y);
                acc[2] += al * bf2f(vs.z);
                acc[3] += al * bf2f(vs.w);
            } else {
                short8 vs = *(const short8*)(fs + (size_t)s * HD + lane * 8);
                #pragma unroll
                for (int k = 0; k < 8; ++k) acc[k] += al * bf2f((unsigned short)vs[k]);
            }
        }
        // head-max across the 4 head groups (lanes l, l^16, l^32, l^48)
        #pragma unroll
        for (int k = 0; k < VE; ++k) {
            acc[k] = fmaxf(acc[k], __shfl_xor(acc[k], 16));
            acc[k] = fmaxf(acc[k], __shfl_xor(acc[k], 32));
        }
        if (lane < 16) {
            if constexpr (VE == 4) {
                ushort4 o;
                o.x = f2bf(acc[0]); o.y = f2bf(acc[1]); o.z = f2bf(acc[2]); o.w = f2bf(acc[3]);
                *(ushort4*)((unsigned short*)hout + (size_t)n * 64 + doff) = o;
            } else {
                float* hp = (float*)hout + (size_t)n * 128 + doff;
                *(float4*)hp = make_float4(acc[0], acc[1], acc[2], acc[3]);
                *(float4*)(hp + 4) = make_float4(acc[4], acc[5], acc[6], acc[7]);
            }
        }
    }
}

// ---------------- global attention pooling: one block per graph ----------------
__global__ void pool_kernel(const float* __restrict__ h2, const float* __restrict__ gate_w,
                            const float* __restrict__ gate_b, float* __restrict__ out) {
    __shared__ float gate[NODE];
    __shared__ float red[256];
    int g = blockIdx.x;
    int tid = threadIdx.x;
    const float* hb = h2 + (size_t)g * NODE * 128;
    float gb = gate_b[0];
    for (int n = tid; n < NODE; n += 256) {
        const float* r = hb + (size_t)n * 128;
        float acc = 0.f;
        #pragma unroll 8
        for (int k = 0; k < 128; ++k) acc += r[k] * gate_w[k];
        gate[n] = acc + gb;
    }
    __syncthreads();
    float m = -INFINITY;
    for (int n = tid; n < NODE; n += 256) m = fmaxf(m, gate[n]);
    red[tid] = m;
    __syncthreads();
    for (int s = 128; s > 0; s >>= 1) {
        if (tid < s) red[tid] = fmaxf(red[tid], red[tid + s]);
        __syncthreads();
    }
    m = red[0];
    __syncthreads();
    float ssum = 0.f;
    for (int n = tid; n < NODE; n += 256) {
        float e = __expf(gate[n] - m);
        gate[n] = e;
        ssum += e;
    }
    red[tid] = ssum;
    __syncthreads();
    for (int s = 128; s > 0; s >>= 1) {
        if (tid < s) red[tid] += red[tid + s];
        __syncthreads();
    }
    float inv = 1.f / red[0];
    __syncthreads();
    if (tid < 128) {
        float acc = 0.f;
        for (int n = 0; n < NODE; ++n) acc += gate[n] * hb[(size_t)n * 128 + tid];
        out[g * 128 + tid] = acc * inv;
    }
}

extern "C" void kernel_launch(void* const* d_in, const int* in_sizes, int n_in,
                              void* d_out, int out_size, void* d_ws, size_t ws_size,
                              hipStream_t stream) {
    const float* x      = (const float*)d_in[0];
    const int*   src    = (const int*)d_in[1];
    const int*   dst    = (const int*)d_in[2];
    // d_in[3] node2graph: implicit (contiguous blocks of 1000)
    const float* W_src1 = (const float*)d_in[4];
    const float* b_src1 = (const float*)d_in[5];
    const float* W_dst1 = (const float*)d_in[6];
    const float* b_dst1 = (const float*)d_in[7];
    const float* attn1  = (const float*)d_in[8];
    const float* W_src2 = (const float*)d_in[9];
    const float* b_src2 = (const float*)d_in[10];
    const float* W_dst2 = (const float*)d_in[11];
    const float* b_dst2 = (const float*)d_in[12];
    const float* attn2  = (const float*)d_in[13];
    const float* gate_w = (const float*)d_in[14];
    const float* gate_b = (const float*)d_in[15];
    float* out = (float*)d_out;

    char* p = (char*)d_ws;
    auto alloc = [&](size_t bytes) -> void* {
        void* r = (void*)p;
        p += (bytes + 255) & ~(size_t)255;
        return r;
    };
    unsigned short* fs     = (unsigned short*)alloc((size_t)NN * 512 * 2);
    unsigned short* fd     = (unsigned short*)alloc((size_t)NN * 512 * 2);
    unsigned short* h1     = (unsigned short*)alloc((size_t)NN * 64 * 2);
    float*          h2     = (float*)alloc((size_t)NN * 128 * 4);
    float*          logits = (float*)alloc((size_t)EE * HEADS * 4);
    unsigned short* x_bf   = (unsigned short*)alloc((size_t)NN * 128 * 2);
    unsigned short* Wt1s   = (unsigned short*)alloc((size_t)128 * 256 * 2);
    unsigned short* Wt1d   = (unsigned short*)alloc((size_t)128 * 256 * 2);
    unsigned short* Wt2s   = (unsigned short*)alloc((size_t)64 * 512 * 2);
    unsigned short* Wt2d   = (unsigned short*)alloc((size_t)64 * 512 * 2);
    int*            deg    = (int*)alloc((size_t)NN * 4);
    int*            rowptr = (int*)alloc((size_t)(NN + 1) * 4);
    int*            cursor = (int*)alloc((size_t)NN * 4);
    int*            eidx   = (int*)alloc((size_t)EE * 4);
    int*            bsum   = (int*)alloc(4096);

    // ---- dtype prep ----
    cvt_f32_bf16<<<(NN * 128 / 4 + 255) / 256, 256, 0, stream>>>(x, x_bf, NN * 128 / 4);
    wt_cvt<<<(128 * 256 + 255) / 256, 256, 0, stream>>>(W_src1, Wt1s, 128, 256);
    wt_cvt<<<(128 * 256 + 255) / 256, 256, 0, stream>>>(W_dst1, Wt1d, 128, 256);
    wt_cvt<<<(64 * 512 + 255) / 256, 256, 0, stream>>>(W_src2, Wt2s, 64, 512);
    wt_cvt<<<(64 * 512 + 255) / 256, 256, 0, stream>>>(W_dst2, Wt2d, 64, 512);

    // ---- CSR build (dst-indexed) ----
    hipMemsetAsync(deg, 0, (size_t)NN * 4, stream);
    count_deg<<<(EE + 255) / 256, 256, 0, stream>>>(dst, deg, EE);
    int nb = (NN + 255) / 256;
    scan1<<<nb, 256, 0, stream>>>(deg, bsum, NN);
    scan2<<<1, 64, 0, stream>>>(bsum, nb, rowptr, NN, EE);
    scan3<<<nb, 256, 0, stream>>>(deg, bsum, rowptr, cursor, NN);
    scatter_edges<<<(EE + 255) / 256, 256, 0, stream>>>(dst, cursor, eidx, EE);

    int rowtiles = (NN + 127) / 128; // 391

    // ---- layer 1 (D=64, HD=256, K=128) ----
    gemm_mfma<128><<<dim3(2, rowtiles), 256, 0, stream>>>(x_bf, Wt1s, b_src1, fs, NN, 256);
    gemm_mfma<128><<<dim3(2, rowtiles), 256, 0, stream>>>(x_bf, Wt1d, b_dst1, fd, NN, 256);
    edge_logits<64><<<2048, 256, 0, stream>>>(fs, fd, src, dst, attn1, logits, EE);
    softmax_alpha<<<(NN * HEADS + 255) / 256, 256, 0, stream>>>(rowptr, eidx, logits, NN);
    aggregate<64><<<2048, 256, 0, stream>>>(rowptr, eidx, src, logits, fs, h1, NN);

    // ---- layer 2 (D=128, HD=512, K=64) ----
    gemm_mfma<64><<<dim3(4, rowtiles), 256, 0, stream>>>(h1, Wt2s, b_src2, fs, NN, 512);
    gemm_mfma<64><<<dim3(4, rowtiles), 256, 0, stream>>>(h1, Wt2d, b_dst2, fd, NN, 512);
    edge_logits<128><<<2048, 256, 0, stream>>>(fs, fd, src, dst, attn2, logits, EE);
    softmax_alpha<<<(NN * HEADS + 255) / 256, 256, 0, stream>>>(rowptr, eidx, logits, NN);
    aggregate<128><<<2048, 256, 0, stream>>>(rowptr, eidx, src, logits, fs, h2, NN);

    // ---- global attention pooling ----
    pool_kernel<<<GG, 256, 0, stream>>>(h2, gate_w, gate_b, out);
}

// Round 8
// 397.217 us; speedup vs baseline: 2.6678x; 1.4094x over previous
//
#include <hip/hip_runtime.h>
#include <math.h>

#define NN 50000
#define GG 50
#define NODE 1000
#define EE 320000
#define HEADS 4

typedef __attribute__((ext_vector_type(8))) short short8;
typedef __attribute__((ext_vector_type(8))) __bf16 bf16x8;
typedef __attribute__((ext_vector_type(4))) float f32x4;

__device__ __forceinline__ unsigned short f2bf(float f) {
    unsigned int u = __float_as_uint(f);
    u = (u + 0x7fffu + ((u >> 16) & 1u)) >> 16;
    return (unsigned short)u;
}
__device__ __forceinline__ float bf2f(unsigned short s) {
    return __uint_as_float(((unsigned int)s) << 16);
}

// ---------------- dtype conversion kernels ----------------
__global__ void cvt_f32_bf16(const float* __restrict__ in, unsigned short* __restrict__ outp, int n4) {
    int i = blockIdx.x * 256 + threadIdx.x;
    if (i < n4) {
        float4 f = *(const float4*)(in + (size_t)i * 4);
        ushort4 o;
        o.x = f2bf(f.x); o.y = f2bf(f.y); o.z = f2bf(f.z); o.w = f2bf(f.w);
        *(ushort4*)(outp + (size_t)i * 4) = o;
    }
}

// W[K][N] fp32 -> Wt[N][K] bf16
__global__ void wt_cvt(const float* __restrict__ W, unsigned short* __restrict__ Wt, int K, int N_) {
    int i = blockIdx.x * 256 + threadIdx.x;
    if (i < K * N_) {
        int n = i / K, k = i - n * K;
        Wt[i] = f2bf(W[(size_t)k * N_ + n]);
    }
}

// ---------------- CSR build ----------------
__global__ void count_deg(const int* __restrict__ dst, int* __restrict__ deg, int E_) {
    int i = blockIdx.x * 256 + threadIdx.x;
    if (i < E_) atomicAdd(&deg[dst[i]], 1);
}

__global__ void scan1(const int* __restrict__ deg, int* __restrict__ bsum, int Nn) {
    __shared__ int sh[256];
    int i = blockIdx.x * 256 + threadIdx.x;
    sh[threadIdx.x] = (i < Nn) ? deg[i] : 0;
    __syncthreads();
    for (int s = 128; s > 0; s >>= 1) {
        if (threadIdx.x < s) sh[threadIdx.x] += sh[threadIdx.x + s];
        __syncthreads();
    }
    if (threadIdx.x == 0) bsum[blockIdx.x] = sh[0];
}

__global__ void scan2(int* __restrict__ bsum, int nb, int* __restrict__ rowptr, int Nn, int E_) {
    if (threadIdx.x == 0 && blockIdx.x == 0) {
        int acc = 0;
        for (int i = 0; i < nb; ++i) { int v = bsum[i]; bsum[i] = acc; acc += v; }
        rowptr[Nn] = E_;
    }
}

__global__ void scan3(const int* __restrict__ deg, const int* __restrict__ bsum,
                      int* __restrict__ rowptr, int* __restrict__ cursor, int Nn) {
    __shared__ int sh[256];
    int i = blockIdx.x * 256 + threadIdx.x;
    int v = (i < Nn) ? deg[i] : 0;
    sh[threadIdx.x] = v;
    __syncthreads();
    for (int s = 1; s < 256; s <<= 1) {
        int t = (threadIdx.x >= s) ? sh[threadIdx.x - s] : 0;
        __syncthreads();
        sh[threadIdx.x] += t;
        __syncthreads();
    }
    if (i < Nn) {
        int ex = sh[threadIdx.x] - v + bsum[blockIdx.x];
        rowptr[i] = ex;
        cursor[i] = ex;
    }
}

// store src node id directly in CSR slot (removes one indirection in the hot loop)
__global__ void scatter_edges(const int* __restrict__ src, const int* __restrict__ dst,
                              int* __restrict__ cursor, int* __restrict__ csrc, int E_) {
    int i = blockIdx.x * 256 + threadIdx.x;
    if (i < E_) { int pos = atomicAdd(&cursor[dst[i]], 1); csrc[pos] = src[i]; }
}

// ---------------- bf16 MFMA GEMM, bf16 output ----------------
// C[M,Ncols](bf16) = A[M,K](bf16) @ Wt[Ncols,K](bf16)^T + bias
template<int K>
__global__ __launch_bounds__(256)
void gemm_mfma(const unsigned short* __restrict__ A, const unsigned short* __restrict__ Wt,
               const float* __restrict__ bias, unsigned short* __restrict__ C,
               int M, int Ncols) {
    __shared__ short A_lds[128 * K];
    __shared__ short B_lds[128 * K];
    constexpr int CH = K / 8;          // 16B chunks per row
    constexpr int ROWB = K * 2;        // bytes per LDS row
    int tid = threadIdx.x;
    int lane = tid & 63, wave = tid >> 6;
    int row0 = blockIdx.y * 128, col0 = blockIdx.x * 128;

    for (int c = tid; c < 128 * CH; c += 256) {
        int r = c / CH, kc = c - r * CH;
        int gr = row0 + r; if (gr >= M) gr = M - 1;
        short8 v = *(const short8*)(A + (size_t)gr * K + kc * 8);
        *(short8*)((char*)A_lds + r * ROWB + ((kc * 16) ^ ((r & 7) << 4))) = v;
    }
    for (int c = tid; c < 128 * CH; c += 256) {
        int r = c / CH, kc = c - r * CH;
        short8 v = *(const short8*)(Wt + (size_t)(col0 + r) * K + kc * 8);
        *(short8*)((char*)B_lds + r * ROWB + ((kc * 16) ^ ((r & 7) << 4))) = v;
    }
    __syncthreads();

    int wr = wave >> 1, wc = wave & 1;
    f32x4 acc[4][4] = {};
    #pragma unroll
    for (int ks = 0; ks < K / 32; ++ks) {
        int kbyte = ks * 64 + ((lane >> 4) << 4);
        short8 a[4], b[4];
        #pragma unroll
        for (int m = 0; m < 4; ++m) {
            int r = wr * 64 + m * 16 + (lane & 15);
            a[m] = *(const short8*)((const char*)A_lds + r * ROWB + (kbyte ^ ((r & 7) << 4)));
        }
        #pragma unroll
        for (int n = 0; n < 4; ++n) {
            int r = wc * 64 + n * 16 + (lane & 15);
            b[n] = *(const short8*)((const char*)B_lds + r * ROWB + (kbyte ^ ((r & 7) << 4)));
        }
        #pragma unroll
        for (int m = 0; m < 4; ++m)
            #pragma unroll
            for (int n = 0; n < 4; ++n)
                acc[m][n] = __builtin_amdgcn_mfma_f32_16x16x32_bf16(
                    __builtin_bit_cast(bf16x8, a[m]), __builtin_bit_cast(bf16x8, b[n]),
                    acc[m][n], 0, 0, 0);
    }

    // epilogue: D mapping col=lane&15, row=(lane>>4)*4+q ; write bf16
    #pragma unroll
    for (int m = 0; m < 4; ++m) {
        int grb = row0 + wr * 64 + m * 16 + ((lane >> 4) << 2);
        #pragma unroll
        for (int q = 0; q < 4; ++q) {
            int gr = grb + q;
            if (gr < M) {
                #pragma unroll
                for (int n = 0; n < 4; ++n) {
                    int gc = col0 + wc * 64 + n * 16 + (lane & 15);
                    C[(size_t)gr * Ncols + gc] = f2bf(acc[m][n][q] + bias[gc]);
                }
            }
        }
    }
}

// ---------------- fused GATv2 edge phase: one wave per dst node ----------------
// Flash-style online softmax: per neighbor, fs[src] row is read ONCE and used for
// both the logit and the rescaled accumulation. fd[dst] read once per node.
// Lane map: head = lane>>4, dims (lane&15)*VE .. +VE-1.
// D=64 -> hout bf16 [NN][64]; D=128 -> hout f32 [NN][128]
template<int D>
__global__ void gat_fused(const int* __restrict__ rowptr, const int* __restrict__ csrc,
                          const unsigned short* __restrict__ fs, const unsigned short* __restrict__ fd,
                          const float* __restrict__ attn, void* __restrict__ hout, int Nn) {
    int lane = threadIdx.x & 63;
    int wave = (blockIdx.x * blockDim.x + threadIdx.x) >> 6;
    int nw = (gridDim.x * blockDim.x) >> 6;
    constexpr int VE = D / 16;
    constexpr int HD = HEADS * D;
    int head = lane >> 4;
    int doff = (lane & 15) * VE;

    float at[VE];
    #pragma unroll
    for (int j = 0; j < VE; ++j) at[j] = attn[head * D + doff + j];

    for (int n = wave; n < Nn; n += nw) {
        int b = rowptr[n], e_ = rowptr[n + 1];
        float r[VE];
        if (b == e_) {
            #pragma unroll
            for (int k = 0; k < VE; ++k) r[k] = 0.f;
        } else {
            // fd row chunk (once per node)
            float fdf[VE];
            if constexpr (VE == 4) {
                ushort4 vd = *(const ushort4*)(fd + (size_t)n * HD + lane * 4);
                fdf[0] = bf2f(vd.x); fdf[1] = bf2f(vd.y); fdf[2] = bf2f(vd.z); fdf[3] = bf2f(vd.w);
            } else {
                short8 vd = *(const short8*)(fd + (size_t)n * HD + lane * 8);
                #pragma unroll
                for (int k = 0; k < 8; ++k) fdf[k] = bf2f((unsigned short)vd[k]);
            }
            float m = -INFINITY, l = 0.f;
            float acc[VE];
            #pragma unroll
            for (int k = 0; k < VE; ++k) acc[k] = 0.f;

            for (int j = b; j < e_; ++j) {
                int s = csrc[j];
                float fsf[VE];
                if constexpr (VE == 4) {
                    ushort4 vs = *(const ushort4*)(fs + (size_t)s * HD + lane * 4);
                    fsf[0] = bf2f(vs.x); fsf[1] = bf2f(vs.y); fsf[2] = bf2f(vs.z); fsf[3] = bf2f(vs.w);
                } else {
                    short8 vs = *(const short8*)(fs + (size_t)s * HD + lane * 8);
                    #pragma unroll
                    for (int k = 0; k < 8; ++k) fsf[k] = bf2f((unsigned short)vs[k]);
                }
                // logit partial: a . LeakyReLU(fs + fd)
                float p = 0.f;
                #pragma unroll
                for (int k = 0; k < VE; ++k) {
                    float v = fsf[k] + fdf[k];
                    v = v >= 0.f ? v : 0.2f * v;
                    p += v * at[k];
                }
                p += __shfl_xor(p, 1);
                p += __shfl_xor(p, 2);
                p += __shfl_xor(p, 4);
                p += __shfl_xor(p, 8);
                // online softmax update
                float mn = fmaxf(m, p);
                float sc = __expf(m - mn);   // 0 on first iter (m = -inf)
                float pw = __expf(p - mn);
                l = l * sc + pw;
                #pragma unroll
                for (int k = 0; k < VE; ++k) acc[k] = acc[k] * sc + pw * fsf[k];
                m = mn;
            }
            float inv = 1.f / l;
            #pragma unroll
            for (int k = 0; k < VE; ++k) r[k] = acc[k] * inv;
        }
        // head-max across the 4 head groups (lanes l, l^16, l^32, l^48)
        #pragma unroll
        for (int k = 0; k < VE; ++k) {
            r[k] = fmaxf(r[k], __shfl_xor(r[k], 16));
            r[k] = fmaxf(r[k], __shfl_xor(r[k], 32));
        }
        if (lane < 16) {
            if constexpr (VE == 4) {
                ushort4 o;
                o.x = f2bf(r[0]); o.y = f2bf(r[1]); o.z = f2bf(r[2]); o.w = f2bf(r[3]);
                *(ushort4*)((unsigned short*)hout + (size_t)n * 64 + doff) = o;
            } else {
                float* hp = (float*)hout + (size_t)n * 128 + doff;
                *(float4*)hp = make_float4(r[0], r[1], r[2], r[3]);
                *(float4*)(hp + 4) = make_float4(r[4], r[5], r[6], r[7]);
            }
        }
    }
}

// ---------------- global attention pooling: one block per graph ----------------
__global__ void pool_kernel(const float* __restrict__ h2, const float* __restrict__ gate_w,
                            const float* __restrict__ gate_b, float* __restrict__ out) {
    __shared__ float gate[NODE];
    __shared__ float red[256];
    int g = blockIdx.x;
    int tid = threadIdx.x;
    const float* hb = h2 + (size_t)g * NODE * 128;
    float gb = gate_b[0];
    for (int n = tid; n < NODE; n += 256) {
        const float* r = hb + (size_t)n * 128;
        float acc = 0.f;
        #pragma unroll 8
        for (int k = 0; k < 128; ++k) acc += r[k] * gate_w[k];
        gate[n] = acc + gb;
    }
    __syncthreads();
    float m = -INFINITY;
    for (int n = tid; n < NODE; n += 256) m = fmaxf(m, gate[n]);
    red[tid] = m;
    __syncthreads();
    for (int s = 128; s > 0; s >>= 1) {
        if (tid < s) red[tid] = fmaxf(red[tid], red[tid + s]);
        __syncthreads();
    }
    m = red[0];
    __syncthreads();
    float ssum = 0.f;
    for (int n = tid; n < NODE; n += 256) {
        float e = __expf(gate[n] - m);
        gate[n] = e;
        ssum += e;
    }
    red[tid] = ssum;
    __syncthreads();
    for (int s = 128; s > 0; s >>= 1) {
        if (tid < s) red[tid] += red[tid + s];
        __syncthreads();
    }
    float inv = 1.f / red[0];
    __syncthreads();
    if (tid < 128) {
        float acc = 0.f;
        for (int n = 0; n < NODE; ++n) acc += gate[n] * hb[(size_t)n * 128 + tid];
        out[g * 128 + tid] = acc * inv;
    }
}

extern "C" void kernel_launch(void* const* d_in, const int* in_sizes, int n_in,
                              void* d_out, int out_size, void* d_ws, size_t ws_size,
                              hipStream_t stream) {
    const float* x      = (const float*)d_in[0];
    const int*   src    = (const int*)d_in[1];
    const int*   dst    = (const int*)d_in[2];
    // d_in[3] node2graph: implicit (contiguous blocks of 1000)
    const float* W_src1 = (const float*)d_in[4];
    const float* b_src1 = (const float*)d_in[5];
    const float* W_dst1 = (const float*)d_in[6];
    const float* b_dst1 = (const float*)d_in[7];
    const float* attn1  = (const float*)d_in[8];
    const float* W_src2 = (const float*)d_in[9];
    const float* b_src2 = (const float*)d_in[10];
    const float* W_dst2 = (const float*)d_in[11];
    const float* b_dst2 = (const float*)d_in[12];
    const float* attn2  = (const float*)d_in[13];
    const float* gate_w = (const float*)d_in[14];
    const float* gate_b = (const float*)d_in[15];
    float* out = (float*)d_out;

    char* p = (char*)d_ws;
    auto alloc = [&](size_t bytes) -> void* {
        void* r = (void*)p;
        p += (bytes + 255) & ~(size_t)255;
        return r;
    };
    unsigned short* fs     = (unsigned short*)alloc((size_t)NN * 512 * 2);
    unsigned short* fd     = (unsigned short*)alloc((size_t)NN * 512 * 2);
    unsigned short* h1     = (unsigned short*)alloc((size_t)NN * 64 * 2);
    float*          h2     = (float*)alloc((size_t)NN * 128 * 4);
    unsigned short* x_bf   = (unsigned short*)alloc((size_t)NN * 128 * 2);
    unsigned short* Wt1s   = (unsigned short*)alloc((size_t)128 * 256 * 2);
    unsigned short* Wt1d   = (unsigned short*)alloc((size_t)128 * 256 * 2);
    unsigned short* Wt2s   = (unsigned short*)alloc((size_t)64 * 512 * 2);
    unsigned short* Wt2d   = (unsigned short*)alloc((size_t)64 * 512 * 2);
    int*            deg    = (int*)alloc((size_t)NN * 4);
    int*            rowptr = (int*)alloc((size_t)(NN + 1) * 4);
    int*            cursor = (int*)alloc((size_t)NN * 4);
    int*            csrc   = (int*)alloc((size_t)EE * 4);
    int*            bsum   = (int*)alloc(4096);

    // ---- dtype prep ----
    cvt_f32_bf16<<<(NN * 128 / 4 + 255) / 256, 256, 0, stream>>>(x, x_bf, NN * 128 / 4);
    wt_cvt<<<(128 * 256 + 255) / 256, 256, 0, stream>>>(W_src1, Wt1s, 128, 256);
    wt_cvt<<<(128 * 256 + 255) / 256, 256, 0, stream>>>(W_dst1, Wt1d, 128, 256);
    wt_cvt<<<(64 * 512 + 255) / 256, 256, 0, stream>>>(W_src2, Wt2s, 64, 512);
    wt_cvt<<<(64 * 512 + 255) / 256, 256, 0, stream>>>(W_dst2, Wt2d, 64, 512);

    // ---- CSR build (dst-indexed, src pre-gathered) ----
    hipMemsetAsync(deg, 0, (size_t)NN * 4, stream);
    count_deg<<<(EE + 255) / 256, 256, 0, stream>>>(dst, deg, EE);
    int nb = (NN + 255) / 256;
    scan1<<<nb, 256, 0, stream>>>(deg, bsum, NN);
    scan2<<<1, 64, 0, stream>>>(bsum, nb, rowptr, NN, EE);
    scan3<<<nb, 256, 0, stream>>>(deg, bsum, rowptr, cursor, NN);
    scatter_edges<<<(EE + 255) / 256, 256, 0, stream>>>(src, dst, cursor, csrc, EE);

    int rowtiles = (NN + 127) / 128; // 391

    // ---- layer 1 (D=64, HD=256, K=128) ----
    gemm_mfma<128><<<dim3(2, rowtiles), 256, 0, stream>>>(x_bf, Wt1s, b_src1, fs, NN, 256);
    gemm_mfma<128><<<dim3(2, rowtiles), 256, 0, stream>>>(x_bf, Wt1d, b_dst1, fd, NN, 256);
    gat_fused<64><<<2048, 256, 0, stream>>>(rowptr, csrc, fs, fd, attn1, h1, NN);

    // ---- layer 2 (D=128, HD=512, K=64) ----
    gemm_mfma<64><<<dim3(4, rowtiles), 256, 0, stream>>>(h1, Wt2s, b_src2, fs, NN, 512);
    gemm_mfma<64><<<dim3(4, rowtiles), 256, 0, stream>>>(h1, Wt2d, b_dst2, fd, NN, 512);
    gat_fused<128><<<2048, 256, 0, stream>>>(rowptr, csrc, fs, fd, attn2, h2, NN);

    // ---- global attention pooling ----
    pool_kernel<<<GG, 256, 0, stream>>>(h2, gate_w, gate_b, out);
}